// Round 17
// baseline (48.472 us; speedup 1.0000x reference)
//
#include <hip/hip_runtime.h>
#include <hip/hip_fp16.h>
#include <math.h>

#define BB 8
#define CC 64
#define NN 8192
#define KK 20
#define COUT 64
#define BN_EPS 1e-5

typedef _Float16 f16x8 __attribute__((ext_vector_type(8)));
typedef _Float16 f16x4 __attribute__((ext_vector_type(4)));
typedef float f32x4 __attribute__((ext_vector_type(4)));

// XCD swizzle: blockIdx round-robins over 8 XCDs -> (blockIdx.x & 7) == XCD.
// Batch b pinned to XCD b keeps b's yc slice resident in that XCD's L2.

// ---------------------------------------------------------------------------
// Pass 1 (fused weight-prep + transpose + MFMA):
//   yc[b][n][o2] fp16 = sum_c x[b][c][n] * wt[o2][c]
//   wt[o2][c] = (o2<64) ? w[o2][c]-w[o2][64+c] : w[o2-64][64+c]
// ---------------------------------------------------------------------------
__global__ __launch_bounds__(256) void pass1_mfma(const float* __restrict__ x,
                                                  const float* __restrict__ w,
                                                  _Float16* __restrict__ yc) {
    const int blk = blockIdx.x;            // 1024 blocks
    const int b   = blk & 7;
    const int ng  = blk >> 3;              // 0..127
    const int n0  = ng * 64;
    const int tid = threadIdx.x;
    const int wv  = __builtin_amdgcn_readfirstlane(tid >> 6);
    const int lane = tid & 63;

    __shared__ float T[64][65];                 // T[c][n]
    __shared__ alignas(16) _Float16 W[128][72]; // W[o2][c]

#pragma unroll
    for (int i = 0; i < 32; ++i) {
        const int idx = i * 256 + tid;
        const int o2 = idx >> 6;
        const int c  = idx & 63;
        float v;
        if (o2 < 64) v = w[o2 * 128 + c] - w[o2 * 128 + 64 + c];
        else         v = w[(o2 - 64) * 128 + 64 + c];
        W[o2][c] = (_Float16)v;
    }
    for (int c = wv; c < 64; c += 4)
        T[c][lane] = x[((size_t)b * CC + c) * NN + n0 + lane];
    __syncthreads();

    const int lr = lane & 15;
    const int lg = lane >> 4;

    f16x8 a0, a1;
#pragma unroll
    for (int j = 0; j < 8; ++j) {
        a0[j] = (_Float16)T[lg * 8 + j][wv * 16 + lr];
        a1[j] = (_Float16)T[32 + lg * 8 + j][wv * 16 + lr];
    }

    f32x4 acc[8];
#pragma unroll
    for (int ob = 0; ob < 8; ++ob) {
        const f16x8 b0 = *reinterpret_cast<const f16x8*>(&W[ob * 16 + lr][lg * 8]);
        const f16x8 b1 = *reinterpret_cast<const f16x8*>(&W[ob * 16 + lr][32 + lg * 8]);
        f32x4 c_ = {0.f, 0.f, 0.f, 0.f};
        c_ = __builtin_amdgcn_mfma_f32_16x16x32_f16(a0, b0, c_, 0, 0, 0);
        c_ = __builtin_amdgcn_mfma_f32_16x16x32_f16(a1, b1, c_, 0, 0, 0);
        acc[ob] = c_;
    }

    _Float16* ybase = yc + ((size_t)b * NN + n0 + wv * 16 + lg * 4) * 128 + lr;
#pragma unroll
    for (int ob = 0; ob < 8; ++ob)
#pragma unroll
        for (int r = 0; r < 4; ++r)
            ybase[(size_t)r * 128 + ob * 16] = (_Float16)acc[ob][r];
}

// ---------------------------------------------------------------------------
// Pass 2 (16B gathers + LDS-staged indices):
// lane = (nsub = lane>>3, q8 = lane&7); each lane owns one n and channel
// octet q8 (16B), iterating all 20 k. Block's 2x640 indices staged in LDS
// via a 320-int4 grid-stride loop. E1 <- edge_index[1] (x_i, wa half),
// E0 <- edge_index[0] (x_j, wb half) — round-16 bug had these SWAPPED.
// 40 f16x8 gathers/lane = 1KB/wave-instr. Packed fp16 max/min; 2x f32x4
// sum/ssq; cross-lane reduce once per wave. hmm fp16 row = [64 max][64 min].
// ---------------------------------------------------------------------------
__global__ __launch_bounds__(256, 4) void pass2_gather(const _Float16* __restrict__ yc,
                                                       const int* __restrict__ eidx,
                                                       __half* __restrict__ hmm,
                                                       float* __restrict__ psum,
                                                       float* __restrict__ pssq) {
    const int b  = blockIdx.x & 7;
    const int n0 = (blockIdx.x >> 3) * 32;
    const int tid = threadIdx.x;
    const int w    = tid >> 6;
    const int lane = tid & 63;
    const int nsub = lane >> 3;   // 0..7: which n this lane serves
    const int q8   = lane & 7;    // channel octet

    __shared__ alignas(16) int E1[640], E0[640];

    // stage this block's indices (rows n0..n0+31 = 640 contiguous ints each):
    // edge_index[1] -> E1 (x_i / wa), edge_index[0] -> E0 (x_j / wb).
    {
        const int4* s1 = reinterpret_cast<const int4*>(
            eidx + (size_t)BB * NN * KK + (size_t)b * NN * KK + (size_t)n0 * KK);
        const int4* s0 = reinterpret_cast<const int4*>(
            eidx + (size_t)b * NN * KK + (size_t)n0 * KK);
        for (int i = tid; i < 320; i += 256) {
            if (i < 160) *reinterpret_cast<int4*>(&E1[i * 4]) = s1[i];
            else         *reinterpret_cast<int4*>(&E0[(i - 160) * 4]) = s0[i - 160];
        }
    }
    __syncthreads();

    const int nl = w * 8 + nsub;        // local n index 0..31
    const int n  = n0 + nl;
    const _Float16* ycB = yc + (size_t)b * NN * 128;   // block-uniform -> SGPR
    const int qo1 = 8 * q8;         // wa octet offset
    const int qo0 = 64 + 8 * q8;    // wb octet offset

    int i1k[20], i0k[20];
#pragma unroll
    for (int c4 = 0; c4 < 5; ++c4) {
        int4 a = *reinterpret_cast<const int4*>(&E1[nl * 20 + 4 * c4]);
        i1k[4 * c4 + 0] = a.x; i1k[4 * c4 + 1] = a.y;
        i1k[4 * c4 + 2] = a.z; i1k[4 * c4 + 3] = a.w;
        int4 c = *reinterpret_cast<const int4*>(&E0[nl * 20 + 4 * c4]);
        i0k[4 * c4 + 0] = c.x; i0k[4 * c4 + 1] = c.y;
        i0k[4 * c4 + 2] = c.z; i0k[4 * c4 + 3] = c.w;
    }

    f16x8 hmx, hmn;
#pragma unroll
    for (int j = 0; j < 8; ++j) { hmx[j] = (_Float16)-65504.f; hmn[j] = (_Float16)65504.f; }
    f32x4 sumA = {0.f, 0.f, 0.f, 0.f}, sumB = {0.f, 0.f, 0.f, 0.f};
    f32x4 ssqA = {0.f, 0.f, 0.f, 0.f}, ssqB = {0.f, 0.f, 0.f, 0.f};

#pragma unroll
    for (int k = 0; k < KK; ++k) {
        f16x8 v1 = *reinterpret_cast<const f16x8*>(ycB + ((i1k[k] << 7) + qo1));
        f16x8 v0 = *reinterpret_cast<const f16x8*>(ycB + ((i0k[k] << 7) + qo0));
        f16x8 h = v1 + v0;                       // 4x v_pk_add_f16
        hmx = __builtin_elementwise_max(hmx, h); // 4x v_pk_max_f16
        hmn = __builtin_elementwise_min(hmn, h);
        f32x4 hA = {(float)h[0], (float)h[1], (float)h[2], (float)h[3]};
        f32x4 hB = {(float)h[4], (float)h[5], (float)h[6], (float)h[7]};
        sumA += hA; sumB += hB;
        ssqA = __builtin_elementwise_fma(hA, hA, ssqA);
        ssqB = __builtin_elementwise_fma(hB, hB, ssqB);
    }

    // store max/min octets (16B each)
    union { f16x8 v; uint4 u; } px, pn;
    px.v = hmx; pn.v = hmn;
    __half* row = hmm + ((size_t)b * NN + n) * 128;
    *reinterpret_cast<uint4*>(row + qo1)      = px.u;
    *reinterpret_cast<uint4*>(row + 64 + qo1) = pn.u;

    // cross-lane sum/ssq reduce over the 8 nsub groups (once per wave)
#pragma unroll
    for (int m = 8; m <= 32; m <<= 1) {
#pragma unroll
        for (int i = 0; i < 4; ++i) {
            sumA[i] += __shfl_xor(sumA[i], m);
            sumB[i] += __shfl_xor(sumB[i], m);
            ssqA[i] += __shfl_xor(ssqA[i], m);
            ssqB[i] += __shfl_xor(ssqB[i], m);
        }
    }
    __shared__ float rs[4][64], rq[4][64];
    if (nsub == 0) {   // lanes 0..7 hold channels 8*q8 .. 8*q8+7
        *reinterpret_cast<f32x4*>(&rs[w][8 * q8])     = sumA;
        *reinterpret_cast<f32x4*>(&rs[w][8 * q8 + 4]) = sumB;
        *reinterpret_cast<f32x4*>(&rq[w][8 * q8])     = ssqA;
        *reinterpret_cast<f32x4*>(&rq[w][8 * q8 + 4]) = ssqB;
    }
    __syncthreads();
    if (w == 0) {
        float s = rs[0][lane] + rs[1][lane] + rs[2][lane] + rs[3][lane];
        float qq = rq[0][lane] + rq[1][lane] + rq[2][lane] + rq[3][lane];
        psum[(size_t)blockIdx.x * 64 + lane] = s;
        pssq[(size_t)blockIdx.x * 64 + lane] = qq;
    }
}

// ---------------------------------------------------------------------------
// Pass 2b stage 1: 32 blocks reduce the 2048 partial rows -> 32 rows (f64).
// ---------------------------------------------------------------------------
__global__ __launch_bounds__(256) void pass2b_stage1(const float* __restrict__ psum,
                                                     const float* __restrict__ pssq,
                                                     double* __restrict__ p2sum,
                                                     double* __restrict__ p2ssq,
                                                     int nblocks) {
    const int t = threadIdx.x;
    const int c = t & 63, s = t >> 6;
    double sum = 0.0, ssq = 0.0;
    for (int i = blockIdx.x * 4 + s; i < nblocks; i += 32 * 4) {
        sum += (double)psum[(size_t)i * 64 + c];
        ssq += (double)pssq[(size_t)i * 64 + c];
    }
    __shared__ double ds_[4][64], dq_[4][64];
    ds_[s][c] = sum;
    dq_[s][c] = ssq;
    __syncthreads();
    if (s == 0) {
        p2sum[(size_t)blockIdx.x * 64 + c] = ds_[0][c] + ds_[1][c] + ds_[2][c] + ds_[3][c];
        p2ssq[(size_t)blockIdx.x * 64 + c] = dq_[0][c] + dq_[1][c] + dq_[2][c] + dq_[3][c];
    }
}

// ---------------------------------------------------------------------------
// Pass 4 (fused stats finalize + output): wave 0 reduces the 32 partial rows
// -> scale/shift in LDS; out[b][o][n] = relu(scale*hsel + shift).
// ---------------------------------------------------------------------------
__global__ __launch_bounds__(256) void pass4_out(const __half* __restrict__ hmm,
                                                 const double* __restrict__ p2sum,
                                                 const double* __restrict__ p2ssq,
                                                 const float* __restrict__ gamma,
                                                 const float* __restrict__ beta,
                                                 float* __restrict__ out) {
    const int b  = blockIdx.x & 7;
    const int n0 = (blockIdx.x >> 3) * 64;
    const int w    = threadIdx.x >> 6;
    const int lane = threadIdx.x & 63;

    __shared__ float ssc[64], ssh[64];
    __shared__ float ts[64][65];

    if (w == 0) {
        double S = 0.0, Q = 0.0;
        for (int i = 0; i < 32; ++i) {
            S += p2sum[i * 64 + lane];
            Q += p2ssq[i * 64 + lane];
        }
        const double cnt = (double)BB * NN * KK;
        double mean = S / cnt;
        double var  = Q / cnt - mean * mean;
        float scale = (float)((double)gamma[lane] / sqrt(var + BN_EPS));
        float shift = (float)((double)beta[lane] - mean * (double)scale);
        ssc[lane] = scale;
        ssh[lane] = shift;
    }
    __syncthreads();

    const float sc = ssc[lane];
    const float sh = ssh[lane];

    for (int i = 0; i < 16; ++i) {
        const int j = w + 4 * i;
        const __half* row = hmm + ((size_t)b * NN + n0 + j) * 128;
        float hv = (sc >= 0.f) ? __half2float(row[lane])
                               : __half2float(row[64 + lane]);
        ts[j][lane] = fmaxf(0.f, fmaf(sc, hv, sh));
    }
    __syncthreads();
    for (int i = 0; i < 16; ++i) {
        const int o = w + 4 * i;
        out[((size_t)b * COUT + o) * NN + n0 + lane] = ts[lane][o];
    }
}

// ---------------------------------------------------------------------------
extern "C" void kernel_launch(void* const* d_in, const int* in_sizes, int n_in,
                              void* d_out, int out_size, void* d_ws, size_t ws_size,
                              hipStream_t stream) {
    const float* x     = (const float*)d_in[0]; // [B, C, N, 1]
    const float* wgt   = (const float*)d_in[1]; // [64, 128]
    const float* gamma = (const float*)d_in[2]; // [64]
    const float* beta  = (const float*)d_in[3]; // [64]
    const int*   eidx  = (const int*)d_in[4];   // [2, B, N, K]
    float* out = (float*)d_out;                 // [B, 64, N]

    // workspace layout
    _Float16* yc  = (_Float16*)d_ws;                      // B*N*128 fp16 (16 MB)
    __half*   hmm = (__half*)(yc + (size_t)BB * NN * 128);// B*N*128 fp16 (16 MB)
    float*  psum  = (float*)(hmm + (size_t)BB * NN * 128);// 2048*64 f32
    float*  pssq  = psum + (size_t)2048 * 64;
    double* p2sum = (double*)(pssq + (size_t)2048 * 64);  // 32*64 f64
    double* p2ssq = p2sum + 32 * 64;

    const int nblk2 = BB * (NN / 32); // 2048

    hipLaunchKernelGGL(pass1_mfma, dim3(BB * (NN / 64)), dim3(256), 0, stream,
                       x, wgt, yc);
    hipLaunchKernelGGL(pass2_gather, dim3(nblk2), dim3(256), 0, stream,
                       yc, eidx, hmm, psum, pssq);
    hipLaunchKernelGGL(pass2b_stage1, dim3(32), dim3(256), 0, stream,
                       psum, pssq, p2sum, p2ssq, nblk2);
    hipLaunchKernelGGL(pass4_out, dim3(BB * (NN / 64)), dim3(256), 0, stream,
                       hmm, p2sum, p2ssq, gamma, beta, out);
}